// Round 11
// baseline (685.138 us; speedup 1.0000x reference)
//
#include <hip/hip_runtime.h>
#include <hip/hip_bf16.h>
#include <stdint.h>

#define BB 16
#define CC 512
#define CQK 64
#define HH 96
#define WW 96
#define HW (HH*WW)        // 9216
#define NPIX (BB*HW)      // 147456

typedef float f32x4 __attribute__((ext_vector_type(4)));
typedef short s16x8 __attribute__((ext_vector_type(8)));

__device__ __forceinline__ unsigned short f2bf(float f){
    unsigned u = __float_as_uint(f);
    unsigned r = (u + 0x7FFFu + ((u >> 16) & 1u)) >> 16;
    return (unsigned short)r;
}
__device__ __forceinline__ float bf2f(unsigned short h){
    return __uint_as_float(((unsigned)h) << 16);
}
__device__ __forceinline__ void gload16(const void* g, void* l){
    __builtin_amdgcn_global_load_lds((const __attribute__((address_space(1))) unsigned int*)g,
                                     (__attribute__((address_space(3))) unsigned int*)l, 16, 0, 0);
}

// ------- K1: fused  weights->bf16 (blocks 0..639)  +  x->xT,xbf (rest) -------
__global__ __launch_bounds__(256) void k_prep(const float* __restrict__ Wq, const float* __restrict__ Wk,
                                              const float* __restrict__ Wv, unsigned short* __restrict__ Wqkv,
                                              const float* __restrict__ x,
                                              unsigned short* __restrict__ xT,
                                              unsigned short* __restrict__ xbf){
    __shared__ float tile[64][65];
    int bid = blockIdx.x, t = threadIdx.x;
    if (bid < 640){
        const float* src = (bid < 64) ? (Wq + (size_t)bid*512)
                         : (bid < 128) ? (Wk + (size_t)(bid-64)*512)
                                       : (Wv + (size_t)(bid-128)*512);
        unsigned short* dst = Wqkv + (size_t)bid*512;
        for (int c = t; c < 512; c += 256) dst[c] = f2bf(src[c]);
        return;
    }
    int r = bid - 640;
    int nt = r % 144, ct = (r/144) & 7, b = r / 1152;
    const float* xb = x + ((size_t)(b*CC + ct*64))*HW + (size_t)nt*64;
    unsigned short* d2 = xbf + ((size_t)(b*CC + ct*64))*HW + (size_t)nt*64;
    #pragma unroll
    for (int s = 0; s < 4; s++){
        int idx = s*256 + t;
        int ci = idx >> 4, n4 = (idx & 15)*4;
        f32x4 vv = *(const f32x4*)(xb + (size_t)ci*HW + n4);
        *(f32x4*)(&tile[ci][n4]) = vv;
        ushort4 u; u.x=f2bf(vv[0]); u.y=f2bf(vv[1]); u.z=f2bf(vv[2]); u.w=f2bf(vv[3]);
        *(ushort4*)(d2 + (size_t)ci*HW + n4) = u;
    }
    __syncthreads();
    unsigned short* dst = xT + ((size_t)b*HW + (size_t)nt*64)*512 + ct*64;
    #pragma unroll
    for (int s = 0; s < 4; s++){
        int idx = s*256 + t;
        int ni = idx >> 4, c0 = (idx & 15)*4;
        ushort4 u;
        u.x = f2bf(tile[c0  ][ni]); u.y = f2bf(tile[c0+1][ni]);
        u.z = f2bf(tile[c0+2][ni]); u.w = f2bf(tile[c0+3][ni]);
        *(ushort4*)(dst + (size_t)ni*512 + c0) = u;
    }
}

// ------ K3: QKV GEMM, 512 threads (8 waves 2x4), dbuf + counted vmcnt --------
__device__ __forceinline__ void stage_tiles8(const unsigned short* Ag, const unsigned short* Bg,
                                             unsigned short* As, unsigned short* Bs,
                                             int wv, int kt){
    #pragma unroll
    for (int s = 0; s < 2; s++){
        int chunk = wv*2 + s;               // 16 chunks of 8 rows
        gload16(Ag + (size_t)chunk*8*512 + (size_t)kt*64, As + chunk*512);
        gload16(Bg + (size_t)chunk*8*512 + (size_t)kt*64, Bs + chunk*512);
    }
}

__global__ __launch_bounds__(512) void k_gemm(const unsigned short* __restrict__ Wqkv,
                                              const unsigned short* __restrict__ xT,
                                              const float* __restrict__ bq, const float* __restrict__ bk,
                                              const float* __restrict__ bv,
                                              unsigned short* __restrict__ q_t,
                                              unsigned short* __restrict__ k_t,
                                              unsigned short* __restrict__ v){
    __shared__ unsigned short As[2][128*64];
    __shared__ unsigned short Bs[2][128*64];
    int b = blockIdx.z, mt = blockIdx.y, nt = blockIdx.x;
    int t = threadIdx.x, wv = t >> 6, lane = t & 63;
    int wr = wv >> 2, wc = wv & 3;          // 2 x 4 wave grid, 64x32 out per wave
    const unsigned short* Ag = Wqkv + (size_t)(mt*128)*512
                               + (size_t)(lane>>3)*512 + (size_t)(((lane&7) ^ (lane>>3))*8);
    const unsigned short* Bg = xT + ((size_t)b*HW + (size_t)nt*128)*512
                               + (size_t)(lane>>3)*512 + (size_t)(((lane&7) ^ (lane>>3))*8);
    f32x4 acc[4][2] = {};
    stage_tiles8(Ag, Bg, As[0], Bs[0], wv, 0);
    stage_tiles8(Ag, Bg, As[1], Bs[1], wv, 1);
    #pragma unroll
    for (int kt = 0; kt < 8; kt++){
        int cur = kt & 1;
        if (kt < 7) asm volatile("s_waitcnt vmcnt(4)" ::: "memory");
        else        asm volatile("s_waitcnt vmcnt(0)" ::: "memory");
        __builtin_amdgcn_s_barrier();
        asm volatile("" ::: "memory");
        __builtin_amdgcn_s_setprio(1);
        #pragma unroll
        for (int kk = 0; kk < 2; kk++){
            int xr = (((kk*4 + (lane>>4)) ^ (lane&7)) << 3);
            s16x8 af[4], bfr[2];
            #pragma unroll
            for (int i = 0; i < 4; i++) af[i]  = *(const s16x8*)(&As[cur][(wr*64 + i*16 + (lane&15))*64 + xr]);
            #pragma unroll
            for (int j = 0; j < 2; j++) bfr[j] = *(const s16x8*)(&Bs[cur][(wc*32 + j*16 + (lane&15))*64 + xr]);
            #pragma unroll
            for (int i = 0; i < 4; i++)
                #pragma unroll
                for (int j = 0; j < 2; j++)
                    acc[i][j] = __builtin_amdgcn_mfma_f32_16x16x32_bf16(af[i], bfr[j], acc[i][j], 0, 0, 0);
        }
        __builtin_amdgcn_s_setprio(0);
        asm volatile("" ::: "memory");
        __builtin_amdgcn_s_barrier();
        asm volatile("" ::: "memory");
        if (kt < 6) stage_tiles8(Ag, Bg, As[cur], Bs[cur], wv, kt+2);
    }
    if (mt == 0){
        const float* bias = (wr == 0) ? bq : bk;
        unsigned short* dst = (wr == 0) ? q_t : k_t;
        #pragma unroll
        for (int i = 0; i < 4; i++){
            int m0 = i*16 + (lane >> 4)*4;
            f32x4 bb = *(const f32x4*)(bias + m0);
            #pragma unroll
            for (int j = 0; j < 2; j++){
                int n = nt*128 + wc*32 + j*16 + (lane & 15);
                ushort4 u;
                u.x = f2bf(acc[i][j][0] + bb[0]);
                u.y = f2bf(acc[i][j][1] + bb[1]);
                u.z = f2bf(acc[i][j][2] + bb[2]);
                u.w = f2bf(acc[i][j][3] + bb[3]);
                *(ushort4*)(dst + ((size_t)b*HW + n)*64 + m0) = u;
            }
        }
    } else {
        #pragma unroll
        for (int i = 0; i < 4; i++){
            int c0 = (mt-1)*128 + wr*64 + i*16 + (lane >> 4)*4;
            f32x4 bb = *(const f32x4*)(bv + c0);
            #pragma unroll
            for (int j = 0; j < 2; j++){
                int n = nt*128 + wc*32 + j*16 + (lane & 15);
                #pragma unroll
                for (int r = 0; r < 4; r++)
                    v[((size_t)b*CC + c0 + r)*HW + n] = f2bf(acc[i][j][r] + bb[r]);
            }
        }
    }
}

// ---- K4: fused  vT transpose (blocks 0..8191)  +  energies (rest), E bf16 ---
__global__ __launch_bounds__(256) void k_vt_energy(const unsigned short* __restrict__ v,
                                                   unsigned short* __restrict__ vT,
                                                   const unsigned short* __restrict__ q_t,
                                                   const unsigned short* __restrict__ k_t,
                                                   unsigned short* __restrict__ E){
    __shared__ char smem[96*97*4];
    int bid = blockIdx.x, t = threadIdx.x;
    if (bid < 8192){
        unsigned int (*tile)[97] = (unsigned int(*)[97])smem;
        int b = bid >> 9, c = bid & 511;
        const unsigned short* src = v + ((size_t)b*CC + c)*HW;
        unsigned short* dst = vT + ((size_t)b*CC + c)*HW;
        for (int idx = t; idx < HW; idx += 256){
            tile[idx/96][idx%96] = src[idx];
        }
        __syncthreads();
        for (int idx = t; idx < HW; idx += 256){
            int w = idx/96, h = idx%96;
            dst[idx] = (unsigned short)tile[h][w];
        }
        return;
    }
    int idx2 = bid - 8192;
    int y = idx2 % 192, b = idx2 / 192;
    unsigned short* qs = (unsigned short*)smem;          // [96][72]
    unsigned short* ks = qs + 96*72;
    int wv = t >> 6, lane = t & 63;
    int wrow = wv >> 1, wcol = wv & 1;
    int modeW = (y >= 96);
    size_t base, rstride;
    if (!modeW){ base = ((size_t)b*HW + y)*64;                 rstride = (size_t)96*64; }
    else       { base = ((size_t)b*HW + (size_t)(y-96)*96)*64; rstride = 64; }
    #pragma unroll
    for (int s = 0; s < 3; s++){
        int chunk = s*256 + t;              // 0..767
        int row = chunk >> 3, c8 = chunk & 7;
        *(s16x8*)(&qs[row*72 + c8*8]) = *(const s16x8*)(q_t + base + (size_t)row*rstride + c8*8);
        *(s16x8*)(&ks[row*72 + c8*8]) = *(const s16x8*)(k_t + base + (size_t)row*rstride + c8*8);
    }
    __syncthreads();
    f32x4 acc[3][3] = {};
    #pragma unroll
    for (int kk = 0; kk < 2; kk++){
        int ko = kk*32 + (lane >> 4)*8;
        s16x8 af[3], bfr[3];
        #pragma unroll
        for (int i = 0; i < 3; i++) af[i]  = *(const s16x8*)(&qs[(wrow*48 + i*16 + (lane&15))*72 + ko]);
        #pragma unroll
        for (int j = 0; j < 3; j++) bfr[j] = *(const s16x8*)(&ks[(wcol*48 + j*16 + (lane&15))*72 + ko]);
        #pragma unroll
        for (int i = 0; i < 3; i++)
            #pragma unroll
            for (int j = 0; j < 3; j++)
                acc[i][j] = __builtin_amdgcn_mfma_f32_16x16x32_bf16(af[i], bfr[j], acc[i][j], 0, 0, 0);
    }
    #pragma unroll
    for (int i = 0; i < 3; i++){
        #pragma unroll
        for (int j = 0; j < 3; j++){
            #pragma unroll
            for (int r = 0; r < 4; r++){
                int row = wrow*48 + i*16 + (lane >> 4)*4 + r;
                int col = wcol*48 + j*16 + (lane & 15);
                float val = acc[i][j][r];
                size_t pix; int jcol;
                if (!modeW){ pix = (size_t)b*HW + (size_t)row*96 + y; jcol = col;
                             if (row == col) val = -1e30f; }
                else       { pix = (size_t)b*HW + (size_t)(y-96)*96 + row; jcol = 96 + col; }
                E[pix*192 + jcol] = f2bf(val);
            }
        }
    }
}

// ---------------- K6: softmax over 192 (bf16 in), att bf16 out ---------------
__global__ __launch_bounds__(256) void k_softmax(const unsigned short* __restrict__ E,
                                                 unsigned short* __restrict__ att){
    int t = threadIdx.x;
    int g = t & 7;
    size_t pix = (size_t)blockIdx.x*32 + (t >> 3);
    const unsigned short* e = E + pix*192 + g*24;
    s16x8 a[3];
    a[0] = *(const s16x8*)(e);
    a[1] = *(const s16x8*)(e + 8);
    a[2] = *(const s16x8*)(e + 16);
    float vals[24];
    float m = -3e38f;
    #pragma unroll
    for (int s = 0; s < 3; s++)
        #pragma unroll
        for (int q = 0; q < 8; q++){
            float f = bf2f((unsigned short)a[s][q]);
            vals[s*8+q] = f;
            m = fmaxf(m, f);
        }
    #pragma unroll
    for (int d = 1; d < 8; d <<= 1) m = fmaxf(m, __shfl_xor(m, d, 64));
    float sum = 0.f;
    #pragma unroll
    for (int q = 0; q < 24; q++){ vals[q] = __expf(vals[q] - m); sum += vals[q]; }
    #pragma unroll
    for (int d = 1; d < 8; d <<= 1) sum += __shfl_xor(sum, d, 64);
    float inv = 1.0f / sum;
    unsigned short* o = att + pix*192 + g*24;
    #pragma unroll
    for (int s = 0; s < 3; s++){
        s16x8 u;
        #pragma unroll
        for (int q = 0; q < 8; q++) u[q] = (short)f2bf(vals[s*8+q]*inv);
        *(s16x8*)(o + s*8) = u;
    }
}

// ------- K7: aggregation, 64-ch tiles, 4 blocks/CU, swizzled stash -----------
// xx = mh*192 + modeW*96 + y  (att-sharing siblings 192 apart -> same XCD)
// modeW=0: A=vT;  outH[b,c, w*96+h] = sum_u vT[b,c,w,u] * att[..,u]
// modeW=1: A=v;   outW[b,c, h*96+w] = sum_v v[b,c,h,v]  * att[..,96+v]  (in place over v)
// Stash swizzle: value (cl,col) stored at col ^ (((cl>>2)&3)<<3); read back with
// phys granule c8 ^ ((row>>2)&3). Flips col bits 3-4 only -> stays in [0,96).
__global__ __launch_bounds__(256, 4) void k_agg(const unsigned short* __restrict__ v,
                                                const unsigned short* __restrict__ vT,
                                                const unsigned short* __restrict__ att,
                                                unsigned short* __restrict__ outH,
                                                unsigned short* __restrict__ outW){
    __shared__ unsigned short As[64*104];    // 13.3 KB (reused as swizzled output tile)
    __shared__ unsigned short Bs[96*104];    // 20.0 KB
    int b = blockIdx.y, xx = blockIdx.x;
    int mh = xx / 192, r2 = xx % 192, modeW = r2 / 96, y = r2 % 96;
    int t = threadIdx.x, wvv = t >> 6, lane = t & 63;
    const unsigned short* Ag = (modeW ? v : vT) + ((size_t)b*CC + (size_t)mh*64)*HW + (size_t)y*96;
    const unsigned short* Bg; size_t bstride;
    if (!modeW){ Bg = att + ((size_t)b*HW + y)*192;                 bstride = (size_t)96*192; }
    else       { Bg = att + ((size_t)b*HW + (size_t)y*96)*192 + 96; bstride = 192; }
    #pragma unroll
    for (int s = 0; s < 3; s++){
        int chunk = s*256 + t;          // 0..767 = 64 rows x 12 chunks
        int row = chunk/12, c8 = chunk%12;
        *(s16x8*)(&As[row*104 + c8*8]) = *(const s16x8*)(Ag + (size_t)row*HW + c8*8);
    }
    #pragma unroll
    for (int s = 0; s < 5; s++){
        int chunk = s*256 + t;
        if (chunk < 1152){
            int row = chunk/12, c8 = chunk%12;
            *(s16x8*)(&Bs[row*104 + c8*8]) = *(const s16x8*)(Bg + (size_t)row*bstride + c8*8);
        }
    }
    __syncthreads();
    f32x4 acc[6] = {};
    #pragma unroll
    for (int kk = 0; kk < 3; kk++){
        int ko = kk*32 + (lane >> 4)*8;
        s16x8 af, bfr[6];
        af = *(const s16x8*)(&As[(wvv*16 + (lane&15))*104 + ko]);
        #pragma unroll
        for (int j = 0; j < 6; j++) bfr[j] = *(const s16x8*)(&Bs[(j*16 + (lane&15))*104 + ko]);
        #pragma unroll
        for (int j = 0; j < 6; j++)
            acc[j] = __builtin_amdgcn_mfma_f32_16x16x32_bf16(af, bfr[j], acc[j], 0, 0, 0);
    }
    __syncthreads();                         // done reading As/Bs
    #pragma unroll
    for (int j = 0; j < 6; j++){
        int col = j*16 + (lane & 15);
        #pragma unroll
        for (int r = 0; r < 4; r++){
            int cl = wvv*16 + (lane >> 4)*4 + r;
            int sw = ((cl >> 2) & 3) << 3;
            As[cl*104 + (col ^ sw)] = f2bf(acc[j][r]);
        }
    }
    __syncthreads();
    unsigned short* OUT = modeW ? outW : outH;
    size_t obase = ((size_t)b*CC + (size_t)mh*64)*HW + (size_t)y*96;
    #pragma unroll
    for (int s = 0; s < 3; s++){
        int chunk = s*256 + t;          // 0..767 = 64 rows x 12 chunks
        int row = chunk/12, c8 = chunk%12;
        int pg = c8 ^ ((row >> 2) & 3);
        *(s16x8*)(OUT + obase + (size_t)row*HW + c8*8) = *(const s16x8*)(&As[row*104 + pg*8]);
    }
}

// ------- K8: combine out = gamma*(outW + outH^T) + xbf  (all-bf16 reads) -----
__global__ __launch_bounds__(256) void k_combine(const unsigned short* __restrict__ outH,
                                                 const unsigned short* __restrict__ outW,
                                                 const unsigned short* __restrict__ xbf,
                                                 const float* __restrict__ gamma,
                                                 float* __restrict__ out){
    __shared__ float tile[96][97];
    int b = blockIdx.y, c = blockIdx.x, t = threadIdx.x;
    const unsigned short* hp = outH + ((size_t)b*CC + c)*HW;  // [w][h]
    #pragma unroll
    for (int s = 0; s < 9; s++){
        int idx = s*1024 + t*4;
        ushort4 u = *(const ushort4*)(hp + idx);
        int r = idx/96, cc = idx%96;
        tile[r][cc] = bf2f(u.x); tile[r][cc+1] = bf2f(u.y);
        tile[r][cc+2] = bf2f(u.z); tile[r][cc+3] = bf2f(u.w);
    }
    __syncthreads();
    float g = gamma[0];
    size_t base = ((size_t)b*CC + c)*HW;
    #pragma unroll
    for (int s = 0; s < 9; s++){
        int idx = s*1024 + t*4;
        ushort4 uw = *(const ushort4*)(outW + base + idx);
        ushort4 ux = *(const ushort4*)(xbf + base + idx);
        int h = idx/96, w = idx%96;
        f32x4 o;
        o[0] = g*(bf2f(uw.x) + tile[w  ][h]) + bf2f(ux.x);
        o[1] = g*(bf2f(uw.y) + tile[w+1][h]) + bf2f(ux.y);
        o[2] = g*(bf2f(uw.z) + tile[w+2][h]) + bf2f(ux.z);
        o[3] = g*(bf2f(uw.w) + tile[w+3][h]) + bf2f(ux.w);
        *(f32x4*)(out + base + idx) = o;
    }
}

extern "C" void kernel_launch(void* const* d_in, const int* in_sizes, int n_in,
                              void* d_out, int out_size, void* d_ws, size_t ws_size,
                              hipStream_t stream){
    const float* x     = (const float*)d_in[0];
    const float* Wq    = (const float*)d_in[1];
    const float* bq    = (const float*)d_in[2];
    const float* Wk    = (const float*)d_in[3];
    const float* bk    = (const float*)d_in[4];
    const float* Wv    = (const float*)d_in[5];
    const float* bv    = (const float*)d_in[6];
    const float* gamma = (const float*)d_in[7];

    constexpr size_t SZ_BIG = (size_t)BB*CC*HW*2;        // 150,994,944
    constexpr size_t SZ_QK  = (size_t)BB*HW*64*2;        // 18,874,368
    constexpr size_t SZ_ATT = (size_t)BB*HW*192*2;       // 56,623,104

    char* ws = (char*)d_ws;
    unsigned short* xT   = (unsigned short*)(ws);                 // stage 1-2; reused as outH (5-6)
    unsigned short* v    = (unsigned short*)(ws + SZ_BIG);        // stage 2-5; overwritten by outW (5-6)
    unsigned short* xbf  = (unsigned short*)(ws + 2*SZ_BIG);      // stage 1-6
    unsigned short* q_t  = (unsigned short*)(ws + 3*SZ_BIG);
    unsigned short* k_t  = (unsigned short*)(ws + 3*SZ_BIG + SZ_QK);
    unsigned short* att  = (unsigned short*)(ws + 3*SZ_BIG + 2*SZ_QK);
    unsigned short* Wqkv = (unsigned short*)(ws + 3*SZ_BIG + 2*SZ_QK + SZ_ATT);

    // d_out (302MB) doubles as scratch:
    //   E  bf16 [0 .. 57MB)       written stage 3, read stage 4
    //   vT bf16 [151MB .. 302MB)  written stage 3, read stage 5
    //   out f32 [0 .. 302MB)      written stage 6 only
    unsigned short* E    = (unsigned short*)d_out;
    unsigned short* vT   = (unsigned short*)((char*)d_out + SZ_BIG);
    float*          out  = (float*)d_out;
    unsigned short* outH = xT;
    unsigned short* outW = v;            // in-place over v

    k_prep      <<<dim3(19072),    dim3(256), 0, stream>>>(Wq, Wk, Wv, Wqkv, x, xT, xbf);
    k_gemm      <<<dim3(72, 5, 16),dim3(512), 0, stream>>>(Wqkv, xT, bq, bk, bv, q_t, k_t, v);
    k_vt_energy <<<dim3(11264),    dim3(256), 0, stream>>>(v, vT, q_t, k_t, E);
    k_softmax   <<<dim3(4608),     dim3(256), 0, stream>>>(E, att);
    k_agg       <<<dim3(1536, 16), dim3(256), 0, stream>>>(v, vT, att, outH, outW);
    k_combine   <<<dim3(512, 16),  dim3(256), 0, stream>>>(outH, outW, xbf, gamma, out);
}

// Round 13
// 661.779 us; speedup vs baseline: 1.0353x; 1.0353x over previous
//
#include <hip/hip_runtime.h>
#include <hip/hip_bf16.h>
#include <stdint.h>

#define BB 16
#define CC 512
#define CQK 64
#define HH 96
#define WW 96
#define HW (HH*WW)        // 9216
#define NPIX (BB*HW)      // 147456

typedef float f32x4 __attribute__((ext_vector_type(4)));
typedef short s16x8 __attribute__((ext_vector_type(8)));

__device__ __forceinline__ unsigned short f2bf(float f){
    unsigned u = __float_as_uint(f);
    unsigned r = (u + 0x7FFFu + ((u >> 16) & 1u)) >> 16;
    return (unsigned short)r;
}
__device__ __forceinline__ float bf2f(unsigned short h){
    return __uint_as_float(((unsigned)h) << 16);
}
__device__ __forceinline__ void gload16(const void* g, void* l){
    __builtin_amdgcn_global_load_lds((const __attribute__((address_space(1))) unsigned int*)g,
                                     (__attribute__((address_space(3))) unsigned int*)l, 16, 0, 0);
}

// ------- K1: fused  weights->bf16 (blocks 0..639)  +  x->xT,xbf (rest) -------
__global__ __launch_bounds__(256) void k_prep(const float* __restrict__ Wq, const float* __restrict__ Wk,
                                              const float* __restrict__ Wv, unsigned short* __restrict__ Wqkv,
                                              const float* __restrict__ x,
                                              unsigned short* __restrict__ xT,
                                              unsigned short* __restrict__ xbf){
    __shared__ float tile[64][65];
    int bid = blockIdx.x, t = threadIdx.x;
    if (bid < 640){
        const float* src = (bid < 64) ? (Wq + (size_t)bid*512)
                         : (bid < 128) ? (Wk + (size_t)(bid-64)*512)
                                       : (Wv + (size_t)(bid-128)*512);
        unsigned short* dst = Wqkv + (size_t)bid*512;
        for (int c = t; c < 512; c += 256) dst[c] = f2bf(src[c]);
        return;
    }
    int r = bid - 640;
    int nt = r % 144, ct = (r/144) & 7, b = r / 1152;
    const float* xb = x + ((size_t)(b*CC + ct*64))*HW + (size_t)nt*64;
    unsigned short* d2 = xbf + ((size_t)(b*CC + ct*64))*HW + (size_t)nt*64;
    #pragma unroll
    for (int s = 0; s < 4; s++){
        int idx = s*256 + t;
        int ci = idx >> 4, n4 = (idx & 15)*4;
        f32x4 vv = *(const f32x4*)(xb + (size_t)ci*HW + n4);
        *(f32x4*)(&tile[ci][n4]) = vv;
        ushort4 u; u.x=f2bf(vv[0]); u.y=f2bf(vv[1]); u.z=f2bf(vv[2]); u.w=f2bf(vv[3]);
        *(ushort4*)(d2 + (size_t)ci*HW + n4) = u;
    }
    __syncthreads();
    unsigned short* dst = xT + ((size_t)b*HW + (size_t)nt*64)*512 + ct*64;
    #pragma unroll
    for (int s = 0; s < 4; s++){
        int idx = s*256 + t;
        int ni = idx >> 4, c0 = (idx & 15)*4;
        ushort4 u;
        u.x = f2bf(tile[c0  ][ni]); u.y = f2bf(tile[c0+1][ni]);
        u.z = f2bf(tile[c0+2][ni]); u.w = f2bf(tile[c0+3][ni]);
        *(ushort4*)(dst + (size_t)ni*512 + c0) = u;
    }
}

// ------ K3: QKV GEMM, 512 threads (8 waves 2x4), dbuf + counted vmcnt --------
__device__ __forceinline__ void stage_tiles8(const unsigned short* Ag, const unsigned short* Bg,
                                             unsigned short* As, unsigned short* Bs,
                                             int wv, int kt){
    #pragma unroll
    for (int s = 0; s < 2; s++){
        int chunk = wv*2 + s;               // 16 chunks of 8 rows
        gload16(Ag + (size_t)chunk*8*512 + (size_t)kt*64, As + chunk*512);
        gload16(Bg + (size_t)chunk*8*512 + (size_t)kt*64, Bs + chunk*512);
    }
}

__global__ __launch_bounds__(512) void k_gemm(const unsigned short* __restrict__ Wqkv,
                                              const unsigned short* __restrict__ xT,
                                              const float* __restrict__ bq, const float* __restrict__ bk,
                                              const float* __restrict__ bv,
                                              unsigned short* __restrict__ q_t,
                                              unsigned short* __restrict__ k_t,
                                              unsigned short* __restrict__ v){
    __shared__ unsigned short As[2][128*64];
    __shared__ unsigned short Bs[2][128*64];
    int b = blockIdx.z, mt = blockIdx.y, nt = blockIdx.x;
    int t = threadIdx.x, wv = t >> 6, lane = t & 63;
    int wr = wv >> 2, wc = wv & 3;          // 2 x 4 wave grid, 64x32 out per wave
    const unsigned short* Ag = Wqkv + (size_t)(mt*128)*512
                               + (size_t)(lane>>3)*512 + (size_t)(((lane&7) ^ (lane>>3))*8);
    const unsigned short* Bg = xT + ((size_t)b*HW + (size_t)nt*128)*512
                               + (size_t)(lane>>3)*512 + (size_t)(((lane&7) ^ (lane>>3))*8);
    f32x4 acc[4][2] = {};
    stage_tiles8(Ag, Bg, As[0], Bs[0], wv, 0);
    stage_tiles8(Ag, Bg, As[1], Bs[1], wv, 1);
    #pragma unroll
    for (int kt = 0; kt < 8; kt++){
        int cur = kt & 1;
        if (kt < 7) asm volatile("s_waitcnt vmcnt(4)" ::: "memory");
        else        asm volatile("s_waitcnt vmcnt(0)" ::: "memory");
        __builtin_amdgcn_s_barrier();
        asm volatile("" ::: "memory");
        __builtin_amdgcn_s_setprio(1);
        #pragma unroll
        for (int kk = 0; kk < 2; kk++){
            int xr = (((kk*4 + (lane>>4)) ^ (lane&7)) << 3);
            s16x8 af[4], bfr[2];
            #pragma unroll
            for (int i = 0; i < 4; i++) af[i]  = *(const s16x8*)(&As[cur][(wr*64 + i*16 + (lane&15))*64 + xr]);
            #pragma unroll
            for (int j = 0; j < 2; j++) bfr[j] = *(const s16x8*)(&Bs[cur][(wc*32 + j*16 + (lane&15))*64 + xr]);
            #pragma unroll
            for (int i = 0; i < 4; i++)
                #pragma unroll
                for (int j = 0; j < 2; j++)
                    acc[i][j] = __builtin_amdgcn_mfma_f32_16x16x32_bf16(af[i], bfr[j], acc[i][j], 0, 0, 0);
        }
        __builtin_amdgcn_s_setprio(0);
        asm volatile("" ::: "memory");
        __builtin_amdgcn_s_barrier();
        asm volatile("" ::: "memory");
        if (kt < 6) stage_tiles8(Ag, Bg, As[cur], Bs[cur], wv, kt+2);
    }
    if (mt == 0){
        const float* bias = (wr == 0) ? bq : bk;
        unsigned short* dst = (wr == 0) ? q_t : k_t;
        #pragma unroll
        for (int i = 0; i < 4; i++){
            int m0 = i*16 + (lane >> 4)*4;
            f32x4 bb = *(const f32x4*)(bias + m0);
            #pragma unroll
            for (int j = 0; j < 2; j++){
                int n = nt*128 + wc*32 + j*16 + (lane & 15);
                ushort4 u;
                u.x = f2bf(acc[i][j][0] + bb[0]);
                u.y = f2bf(acc[i][j][1] + bb[1]);
                u.z = f2bf(acc[i][j][2] + bb[2]);
                u.w = f2bf(acc[i][j][3] + bb[3]);
                *(ushort4*)(dst + ((size_t)b*HW + n)*64 + m0) = u;
            }
        }
    } else {
        #pragma unroll
        for (int i = 0; i < 4; i++){
            int c0 = (mt-1)*128 + wr*64 + i*16 + (lane >> 4)*4;
            f32x4 bb = *(const f32x4*)(bv + c0);
            #pragma unroll
            for (int j = 0; j < 2; j++){
                int n = nt*128 + wc*32 + j*16 + (lane & 15);
                #pragma unroll
                for (int r = 0; r < 4; r++)
                    v[((size_t)b*CC + c0 + r)*HW + n] = f2bf(acc[i][j][r] + bb[r]);
            }
        }
    }
}

// ---- K4: fused  vT transpose (vectorized, blocks 0..8191) + energies --------
// Transpose tile: [96][128] shorts, granule swizzle pg = g ^ ((row>>3)&7).
__global__ __launch_bounds__(256) void k_vt_energy(const unsigned short* __restrict__ v,
                                                   unsigned short* __restrict__ vT,
                                                   const unsigned short* __restrict__ q_t,
                                                   const unsigned short* __restrict__ k_t,
                                                   unsigned short* __restrict__ E){
    __shared__ char smem[96*72*2*2];        // 27648 B (union: qs/ks | 96x128 tile 24576)
    int bid = blockIdx.x, t = threadIdx.x;
    if (bid < 8192){
        unsigned short* tile = (unsigned short*)smem;   // [96][128] swizzled
        int b = bid >> 9, c = bid & 511;
        const unsigned short* src = v + ((size_t)b*CC + c)*HW;
        unsigned short* dst = vT + ((size_t)b*CC + c)*HW;
        #pragma unroll
        for (int s = 0; s < 5; s++){
            int chunk = s*256 + t;
            if (chunk < 1152){
                int row = chunk/12, g = chunk%12;
                int pg = g ^ ((row>>3)&7);              // < 16, fits 128-col tile
                *(s16x8*)(&tile[row*128 + pg*8]) = *(const s16x8*)(src + chunk*8);
            }
        }
        __syncthreads();
        #pragma unroll
        for (int s = 0; s < 5; s++){
            int c2 = s*256 + t;
            if (c2 < 1152){
                int w = c2/12, h0 = (c2%12)*8;
                s16x8 u;
                #pragma unroll
                for (int k = 0; k < 8; k++){
                    int h = h0 + k;
                    int gw = (w>>3) ^ ((h>>3)&7);
                    u[k] = (short)tile[h*128 + gw*8 + (w&7)];
                }
                *(s16x8*)(dst + (size_t)w*96 + h0) = u;
            }
        }
        return;
    }
    int idx2 = bid - 8192;
    int y = idx2 % 192, b = idx2 / 192;
    unsigned short* qs = (unsigned short*)smem;          // [96][72]
    unsigned short* ks = qs + 96*72;
    int wv = t >> 6, lane = t & 63;
    int wrow = wv >> 1, wcol = wv & 1;
    int modeW = (y >= 96);
    size_t base, rstride;
    if (!modeW){ base = ((size_t)b*HW + y)*64;                 rstride = (size_t)96*64; }
    else       { base = ((size_t)b*HW + (size_t)(y-96)*96)*64; rstride = 64; }
    #pragma unroll
    for (int s = 0; s < 3; s++){
        int chunk = s*256 + t;              // 0..767
        int row = chunk >> 3, c8 = chunk & 7;
        *(s16x8*)(&qs[row*72 + c8*8]) = *(const s16x8*)(q_t + base + (size_t)row*rstride + c8*8);
        *(s16x8*)(&ks[row*72 + c8*8]) = *(const s16x8*)(k_t + base + (size_t)row*rstride + c8*8);
    }
    __syncthreads();
    f32x4 acc[3][3] = {};
    #pragma unroll
    for (int kk = 0; kk < 2; kk++){
        int ko = kk*32 + (lane >> 4)*8;
        s16x8 af[3], bfr[3];
        #pragma unroll
        for (int i = 0; i < 3; i++) af[i]  = *(const s16x8*)(&qs[(wrow*48 + i*16 + (lane&15))*72 + ko]);
        #pragma unroll
        for (int j = 0; j < 3; j++) bfr[j] = *(const s16x8*)(&ks[(wcol*48 + j*16 + (lane&15))*72 + ko]);
        #pragma unroll
        for (int i = 0; i < 3; i++)
            #pragma unroll
            for (int j = 0; j < 3; j++)
                acc[i][j] = __builtin_amdgcn_mfma_f32_16x16x32_bf16(af[i], bfr[j], acc[i][j], 0, 0, 0);
    }
    #pragma unroll
    for (int i = 0; i < 3; i++){
        #pragma unroll
        for (int j = 0; j < 3; j++){
            #pragma unroll
            for (int r = 0; r < 4; r++){
                int row = wrow*48 + i*16 + (lane >> 4)*4 + r;
                int col = wcol*48 + j*16 + (lane & 15);
                float val = acc[i][j][r];
                size_t pix; int jcol;
                if (!modeW){ pix = (size_t)b*HW + (size_t)row*96 + y; jcol = col;
                             if (row == col) val = -1e30f; }
                else       { pix = (size_t)b*HW + (size_t)(y-96)*96 + row; jcol = 96 + col; }
                E[pix*192 + jcol] = f2bf(val);
            }
        }
    }
}

// ---------------- K6: softmax over 192 (bf16 in), att bf16 out ---------------
__global__ __launch_bounds__(256) void k_softmax(const unsigned short* __restrict__ E,
                                                 unsigned short* __restrict__ att){
    int t = threadIdx.x;
    int g = t & 7;
    size_t pix = (size_t)blockIdx.x*32 + (t >> 3);
    const unsigned short* e = E + pix*192 + g*24;
    s16x8 a[3];
    a[0] = *(const s16x8*)(e);
    a[1] = *(const s16x8*)(e + 8);
    a[2] = *(const s16x8*)(e + 16);
    float vals[24];
    float m = -3e38f;
    #pragma unroll
    for (int s = 0; s < 3; s++)
        #pragma unroll
        for (int q = 0; q < 8; q++){
            float f = bf2f((unsigned short)a[s][q]);
            vals[s*8+q] = f;
            m = fmaxf(m, f);
        }
    #pragma unroll
    for (int d = 1; d < 8; d <<= 1) m = fmaxf(m, __shfl_xor(m, d, 64));
    float sum = 0.f;
    #pragma unroll
    for (int q = 0; q < 24; q++){ vals[q] = __expf(vals[q] - m); sum += vals[q]; }
    #pragma unroll
    for (int d = 1; d < 8; d <<= 1) sum += __shfl_xor(sum, d, 64);
    float inv = 1.0f / sum;
    unsigned short* o = att + pix*192 + g*24;
    #pragma unroll
    for (int s = 0; s < 3; s++){
        s16x8 u;
        #pragma unroll
        for (int q = 0; q < 8; q++) u[q] = (short)f2bf(vals[s*8+q]*inv);
        *(s16x8*)(o + s*8) = u;
    }
}

// ------- K7: aggregation, 64-ch tiles, 4-y pipeline, dbuf, 2 blocks/CU -------
// xx = combo*24 + ygrp ; combo = mh*2+modeW, mh in [0,8) -> 16 combos, grid 384
// modeW=0: A=vT;  outH[b,c, w*96+h] = sum_u vT[b,c,w,u] * att[..,u]
// modeW=1: A=v;   outW[b,c, h*96+w] = sum_v v[b,c,h,v]  * att[..,96+v]  (in place over v)
// Pipeline: reg-stage next y's tiles early; ds_write late; raw barriers with
// lgkmcnt(0) only (never vmcnt(0) mid-loop).
__global__ __launch_bounds__(256, 2) void k_agg(const unsigned short* __restrict__ v,
                                                const unsigned short* __restrict__ vT,
                                                const unsigned short* __restrict__ att,
                                                unsigned short* __restrict__ outH,
                                                unsigned short* __restrict__ outW){
    __shared__ unsigned short As[2][64*104];   // 26.6 KB
    __shared__ unsigned short Bs[2][96*104];   // 39.9 KB
    __shared__ unsigned short Os[64*104];      // 13.3 KB  (output stash)
    int b = blockIdx.y, xx = blockIdx.x;
    int combo = xx / 24, ygrp = xx % 24;
    int mh = combo >> 1, modeW = combo & 1;    // mh in [0,8)
    int y0 = ygrp * 4;
    int t = threadIdx.x, wvv = t >> 6, lane = t & 63;
    const unsigned short* Abase = (modeW ? v : vT) + ((size_t)b*CC + (size_t)mh*64)*HW;
    size_t bstride = modeW ? 192 : (size_t)96*192;
    unsigned short* OUT = modeW ? outW : outH;

    int arow[3], ac8[3];
    #pragma unroll
    for (int s = 0; s < 3; s++){ int ch = s*256 + t; arow[s] = ch/12; ac8[s] = ch%12; }
    int brow[5], bc8[5]; bool bok[5];
    #pragma unroll
    for (int s = 0; s < 5; s++){ int ch = s*256 + t; bok[s] = ch < 1152;
        int cc = bok[s] ? ch : 0; brow[s] = cc/12; bc8[s] = cc%12; }

    s16x8 ra[3], rb[5];
    #define ISSUE_LOADS(y) { \
        const unsigned short* Ag = Abase + (size_t)(y)*96; \
        const unsigned short* Bg = modeW ? (att + ((size_t)b*HW + (size_t)(y)*96)*192 + 96) \
                                         : (att + ((size_t)b*HW + (y))*192); \
        _Pragma("unroll") \
        for (int s = 0; s < 3; s++) ra[s] = *(const s16x8*)(Ag + (size_t)arow[s]*HW + ac8[s]*8); \
        _Pragma("unroll") \
        for (int s = 0; s < 5; s++) if (bok[s]) rb[s] = *(const s16x8*)(Bg + (size_t)brow[s]*bstride + bc8[s]*8); \
        asm volatile("" ::: "memory"); }
    #define WRITE_LDS(buf) { \
        _Pragma("unroll") \
        for (int s = 0; s < 3; s++) *(s16x8*)(&As[buf][arow[s]*104 + ac8[s]*8]) = ra[s]; \
        _Pragma("unroll") \
        for (int s = 0; s < 5; s++) if (bok[s]) *(s16x8*)(&Bs[buf][brow[s]*104 + bc8[s]*8]) = rb[s]; \
        asm volatile("" ::: "memory"); }

    ISSUE_LOADS(y0);
    WRITE_LDS(0);                               // compiler waits vmcnt for ra/rb
    ISSUE_LOADS(y0+1);                          // tile1 in flight
    asm volatile("s_waitcnt lgkmcnt(0)" ::: "memory");
    __builtin_amdgcn_s_barrier();
    asm volatile("" ::: "memory");

    #pragma unroll
    for (int i = 0; i < 4; i++){
        int cur = i & 1;
        int y = y0 + i;
        // ---- MFMA on buf[cur] ----
        f32x4 acc[6] = {};
        __builtin_amdgcn_s_setprio(1);
        #pragma unroll
        for (int kk = 0; kk < 3; kk++){
            int ko = kk*32 + (lane >> 4)*8;
            s16x8 af, bfr[6];
            af = *(const s16x8*)(&As[cur][(wvv*16 + (lane&15))*104 + ko]);
            #pragma unroll
            for (int j = 0; j < 6; j++) bfr[j] = *(const s16x8*)(&Bs[cur][(j*16 + (lane&15))*104 + ko]);
            #pragma unroll
            for (int j = 0; j < 6; j++)
                acc[j] = __builtin_amdgcn_mfma_f32_16x16x32_bf16(af, bfr[j], acc[j], 0, 0, 0);
        }
        __builtin_amdgcn_s_setprio(0);
        // ---- stash to Os ----
        #pragma unroll
        for (int j = 0; j < 6; j++){
            int col = j*16 + (lane & 15);
            #pragma unroll
            for (int r = 0; r < 4; r++){
                int cl = wvv*16 + (lane >> 4)*4 + r;
                Os[cl*104 + col] = f2bf(acc[j][r]);
            }
        }
        asm volatile("s_waitcnt lgkmcnt(0)" ::: "memory");
        __builtin_amdgcn_s_barrier();           // Os visible; As/Bs[cur] fully read
        asm volatile("" ::: "memory");
        // ---- coalesced copy-out ----
        size_t obase = ((size_t)b*CC + (size_t)mh*64)*HW + (size_t)y*96;
        #pragma unroll
        for (int s = 0; s < 3; s++){
            int chunk = s*256 + t;
            int row = chunk/12, c8 = chunk%12;
            *(s16x8*)(OUT + obase + (size_t)row*HW + c8*8) = *(const s16x8*)(&Os[row*104 + c8*8]);
        }
        if (i < 3){
            WRITE_LDS(cur^1);                   // tile i+1 -> buf^1 (compiler-counted vmcnt)
            if (i < 2) ISSUE_LOADS(y0+i+2);     // tile i+2 in flight
            asm volatile("s_waitcnt lgkmcnt(0)" ::: "memory");
            __builtin_amdgcn_s_barrier();       // buf^1 ready; loads/stores stay in flight
            asm volatile("" ::: "memory");
        }
    }
    #undef ISSUE_LOADS
    #undef WRITE_LDS
}

// ------- K8: combine out = gamma*(outW + outH^T) + xbf  (all-bf16 reads) -----
__global__ __launch_bounds__(256) void k_combine(const unsigned short* __restrict__ outH,
                                                 const unsigned short* __restrict__ outW,
                                                 const unsigned short* __restrict__ xbf,
                                                 const float* __restrict__ gamma,
                                                 float* __restrict__ out){
    __shared__ float tile[96][97];
    int b = blockIdx.y, c = blockIdx.x, t = threadIdx.x;
    const unsigned short* hp = outH + ((size_t)b*CC + c)*HW;  // [w][h]
    #pragma unroll
    for (int s = 0; s < 9; s++){
        int idx = s*1024 + t*4;
        ushort4 u = *(const ushort4*)(hp + idx);
        int r = idx/96, cc = idx%96;
        tile[r][cc] = bf2f(u.x); tile[r][cc+1] = bf2f(u.y);
        tile[r][cc+2] = bf2f(u.z); tile[r][cc+3] = bf2f(u.w);
    }
    __syncthreads();
    float g = gamma[0];
    size_t base = ((size_t)b*CC + c)*HW;
    #pragma unroll
    for (int s = 0; s < 9; s++){
        int idx = s*1024 + t*4;
        ushort4 uw = *(const ushort4*)(outW + base + idx);
        ushort4 ux = *(const ushort4*)(xbf + base + idx);
        int h = idx/96, w = idx%96;
        f32x4 o;
        o[0] = g*(bf2f(uw.x) + tile[w  ][h]) + bf2f(ux.x);
        o[1] = g*(bf2f(uw.y) + tile[w+1][h]) + bf2f(ux.y);
        o[2] = g*(bf2f(uw.z) + tile[w+2][h]) + bf2f(ux.z);
        o[3] = g*(bf2f(uw.w) + tile[w+3][h]) + bf2f(ux.w);
        *(f32x4*)(out + base + idx) = o;
    }
}

extern "C" void kernel_launch(void* const* d_in, const int* in_sizes, int n_in,
                              void* d_out, int out_size, void* d_ws, size_t ws_size,
                              hipStream_t stream){
    const float* x     = (const float*)d_in[0];
    const float* Wq    = (const float*)d_in[1];
    const float* bq    = (const float*)d_in[2];
    const float* Wk    = (const float*)d_in[3];
    const float* bk    = (const float*)d_in[4];
    const float* Wv    = (const float*)d_in[5];
    const float* bv    = (const float*)d_in[6];
    const float* gamma = (const float*)d_in[7];

    constexpr size_t SZ_BIG = (size_t)BB*CC*HW*2;        // 150,994,944
    constexpr size_t SZ_QK  = (size_t)BB*HW*64*2;        // 18,874,368
    constexpr size_t SZ_ATT = (size_t)BB*HW*192*2;       // 56,623,104

    char* ws = (char*)d_ws;
    unsigned short* xT   = (unsigned short*)(ws);                 // stage 1-2; reused as outH (5-6)
    unsigned short* v    = (unsigned short*)(ws + SZ_BIG);        // stage 2-5; overwritten by outW (5-6)
    unsigned short* xbf  = (unsigned short*)(ws + 2*SZ_BIG);      // stage 1-6
    unsigned short* q_t  = (unsigned short*)(ws + 3*SZ_BIG);
    unsigned short* k_t  = (unsigned short*)(ws + 3*SZ_BIG + SZ_QK);
    unsigned short* att  = (unsigned short*)(ws + 3*SZ_BIG + 2*SZ_QK);
    unsigned short* Wqkv = (unsigned short*)(ws + 3*SZ_BIG + 2*SZ_QK + SZ_ATT);

    // d_out (302MB) doubles as scratch:
    //   E  bf16 [0 .. 57MB)       written stage 3, read stage 4
    //   vT bf16 [151MB .. 302MB)  written stage 3, read stage 5
    //   out f32 [0 .. 302MB)      written stage 6 only
    unsigned short* E    = (unsigned short*)d_out;
    unsigned short* vT   = (unsigned short*)((char*)d_out + SZ_BIG);
    float*          out  = (float*)d_out;
    unsigned short* outH = xT;
    unsigned short* outW = v;            // in-place over v

    k_prep      <<<dim3(19072),    dim3(256), 0, stream>>>(Wq, Wk, Wv, Wqkv, x, xT, xbf);
    k_gemm      <<<dim3(72, 5, 16),dim3(512), 0, stream>>>(Wqkv, xT, bq, bk, bv, q_t, k_t, v);
    k_vt_energy <<<dim3(11264),    dim3(256), 0, stream>>>(v, vT, q_t, k_t, E);
    k_softmax   <<<dim3(4608),     dim3(256), 0, stream>>>(E, att);
    k_agg       <<<dim3(384, 16),  dim3(256), 0, stream>>>(v, vT, att, outH, outW);
    k_combine   <<<dim3(512, 16),  dim3(256), 0, stream>>>(outH, outW, xbf, gamma, out);
}